// Round 7
// baseline (398.534 us; speedup 1.0000x reference)
//
#include <hip/hip_runtime.h>
#include <hip/hip_bf16.h>
#include <stdint.h>

#define NB 512
#define NL 128
#define ND 512

typedef __bf16 bf16;
typedef __bf16 bf16x8 __attribute__((ext_vector_type(8)));
typedef float  f32x4  __attribute__((ext_vector_type(4)));

#define GLDS(src, dst) __builtin_amdgcn_global_load_lds( \
    (const __attribute__((address_space(1))) void*)(src), \
    (__attribute__((address_space(3))) void*)(dst), 16, 0, 0)

// ------- K1: gather embed rows -> bf16 + partial sumsq; y==2: att^T ------
// grid (NB, 3, 8), 256 thr. Dedicated high-occupancy BW kernel: the random
// table reads are nontemporal (single-touch; don't evict Ab/Bb from L3,
// which k_mega2 re-reads immediately after).
__global__ __launch_bounds__(256) void k_gather(const int* __restrict__ ctx1,
                                                const int* __restrict__ ctx2,
                                                const float* __restrict__ table,
                                                bf16* __restrict__ d1,
                                                bf16* __restrict__ d2,
                                                float* __restrict__ ss,
                                                const float* __restrict__ att,
                                                bf16* __restrict__ attT) {
    const int b = blockIdx.x, side = blockIdx.y, zc = blockIdx.z, t = threadIdx.x;
    if (side == 2) {                      // att transpose slice
        int chunk = b * 8 + zc;
        if (chunk < 1024) {
            int i = chunk * 256 + t;      // over 512*512
            int n = i >> 9, k = i & 511;
            attT[i] = (bf16)att[k * 512 + n];
        }
        return;
    }
    const int* __restrict__ ctx = side ? ctx2 : ctx1;
    bf16* __restrict__ dst = side ? d2 : d1;
    const int base = b * NL;
    const int dv = t & 127, lr = t >> 7;
    int idxs[8];
    #pragma unroll
    for (int i = 0; i < 8; ++i) idxs[i] = ctx[base + zc * 16 + i * 2 + lr];
    float acc = 0.f;
    #pragma unroll
    for (int i = 0; i < 8; ++i) {
        int l = zc * 16 + i * 2 + lr;
        f32x4 v = __builtin_nontemporal_load(
            (const f32x4*)table + (size_t)idxs[i] * (ND / 4) + dv);
        acc += v[0]*v[0] + v[1]*v[1] + v[2]*v[2] + v[3]*v[3];
        union { bf16 h[4]; uint2 u; } pk;
        pk.h[0] = (bf16)v[0]; pk.h[1] = (bf16)v[1];
        pk.h[2] = (bf16)v[2]; pk.h[3] = (bf16)v[3];
        *((uint2*)(dst + (size_t)(base + l) * ND) + dv) = pk.u;
    }
    for (int o = 32; o; o >>= 1) acc += __shfl_xor(acc, o);
    __shared__ float red[4];
    if ((t & 63) == 0) red[t >> 6] = acc;
    __syncthreads();
    if (t == 0) atomicAdd(&ss[side * NB + b], red[0] + red[1] + red[2] + red[3]);
}

// ---- MEGA2 = R6's compute core, gather removed (Ab/Bb now L3-hot inputs):
//  ph1 : T = A @ attT^T, BK=32 dbuf, counted vmcnt, T -> 128KB swizzled LDS.
//  ph2 : S = tanh(T@B^T*sc) AND G = A@diag(w_pred)@B^T (logit = wrow^T G wcol)
//  Stage tiles bank-conflict-free via source col-slot pre-swizzle ((r>>1)&3).
__global__ __launch_bounds__(512) void k_mega2(
        const bf16* __restrict__ Ab, const bf16* __restrict__ attT,
        const bf16* __restrict__ Bb, float* __restrict__ Sout,
        const float* __restrict__ ss, const float* __restrict__ w_pred,
        const float* __restrict__ b_pred, float* __restrict__ logits) {
    const int b = blockIdx.x, row0 = b * NL, tid = threadIdx.x;
    const int lane = tid & 63, w = tid >> 6;
    const int lm = lane & 15, quad = lane >> 4;
    const int wm  = (w & 1) * 64;             // m-half
    const int wn1 = (w >> 1) * 128;           // ph1 n-chunk (of 512)
    const int wn2 = (w >> 1) * 32;            // ph2 n-chunk (of 128)

    // Arena 160KB: ph1 stages stA dbuf 2x8K @0,8K | stT dbuf 2x32K @16K,48K;
    // Tls [16][128][32] @0..128K (post-ph1); sB dbuf @128K,136K;
    // sC dbuf @144K,152K; S-epilogue smalls alias dead Tls @0.
    __shared__ __align__(16) char smem[163840];
    bf16* stA0 = (bf16*)smem;
    bf16* stA1 = (bf16*)(smem + 8192);
    bf16* stT0 = (bf16*)(smem + 16384);
    bf16* stT1 = (bf16*)(smem + 49152);
    bf16* Tls  = (bf16*)smem;                 // 128K
    bf16* sB0  = (bf16*)(smem + 131072);
    bf16* sB1  = (bf16*)(smem + 139264);
    bf16* sC0  = (bf16*)(smem + 147456);
    bf16* sC1  = (bf16*)(smem + 155648);
    float* rowb = (float*)smem;               // [4][128]
    float* colb = (float*)(smem + 2048);      // [2][128]
    float* wrow = (float*)(smem + 3072);      // [128]
    float* wcol = (float*)(smem + 3584);      // [128]
    float* red2 = (float*)(smem + 4096);      // [8]

    const float ssA = ss[b], ssB = ss[NB + b];

    // stage decomposition: thread -> (row r, 16B slot sl), source col-slot
    // pre-swizzled cs = sl ^ ((r>>1)&3); reader XORs the same.
    #define STAGE1(k0, dA, dT) do {                                          \
        { int r_ = tid >> 2, sl_ = tid & 3, cs_ = sl_ ^ ((r_ >> 1) & 3);     \
          GLDS(Ab + (size_t)(row0 + r_) * ND + (k0) + cs_ * 8, (dA) + tid * 8); } \
        _Pragma("unroll")                                                    \
        for (int i_ = 0; i_ < 4; ++i_) {                                     \
            int s_ = i_ * 512 + tid, r_ = s_ >> 2, sl_ = s_ & 3;             \
            int cs_ = sl_ ^ ((r_ >> 1) & 3);                                 \
            GLDS(attT + (size_t)r_ * ND + (k0) + cs_ * 8, (dT) + s_ * 8); }  \
    } while (0)
    #define STAGE2(k0, dB, dC) do {                                          \
        int r_ = tid >> 2, sl_ = tid & 3, cs_ = sl_ ^ ((r_ >> 1) & 3);       \
        GLDS(Bb + (size_t)(row0 + r_) * ND + (k0) + cs_ * 8, (dB) + tid * 8);\
        GLDS(Ab + (size_t)(row0 + r_) * ND + (k0) + cs_ * 8, (dC) + tid * 8);\
    } while (0)

    // ---------------- Phase 1: T = A @ attT^T (BK=32, dbuf) ----------------
    f32x4 acc1[4][8] = {};
    STAGE1(0, stA0, stT0);                    // prologue: step 0 in flight

    for (int t = 0; t < 16; ++t) {
        if (t < 15) {
            STAGE1((t + 1) * 32, (t & 1) ? stA0 : stA1, (t & 1) ? stT0 : stT1);
            asm volatile("s_waitcnt vmcnt(5)" ::: "memory");   // step t's 5 done
        } else {
            STAGE2(0, sB0, sC0);              // prefetch ph2's first tiles
            asm volatile("s_waitcnt vmcnt(2)" ::: "memory");
        }
        __builtin_amdgcn_s_barrier();
        const bf16* A_ = (t & 1) ? stA1 : stA0;
        const bf16* T_ = (t & 1) ? stT1 : stT0;
        bf16x8 af[4], bfm[8];
        #pragma unroll
        for (int t4 = 0; t4 < 4; ++t4) {
            int R = wm + t4 * 16 + lm;
            af[t4] = *(const bf16x8*)&A_[R * 32 + (quad ^ ((R >> 1) & 3)) * 8];
        }
        #pragma unroll
        for (int t8 = 0; t8 < 8; ++t8) {
            int R = wn1 + t8 * 16 + lm;
            bfm[t8] = *(const bf16x8*)&T_[R * 32 + (quad ^ ((R >> 1) & 3)) * 8];
        }
        __builtin_amdgcn_s_setprio(1);
        #pragma unroll
        for (int im = 0; im < 4; ++im)
            #pragma unroll
            for (int jn = 0; jn < 8; ++jn)
                acc1[im][jn] = __builtin_amdgcn_mfma_f32_16x16x32_bf16(
                    af[im], bfm[jn], acc1[im][jn], 0, 0, 0);
        __builtin_amdgcn_s_setprio(0);
        __builtin_amdgcn_s_barrier();         // buffer reusable next iter
    }

    // Phase-1 epilogue: acc1 -> bf16 swizzled Tls (stage bufs dead).
    // Tls[ks][m][pos][e]: ks=n>>5, kq=(n>>3)&3, e=n&7, pos=kq^((m>>2)&3)
    #pragma unroll
    for (int im = 0; im < 4; ++im)
    #pragma unroll
    for (int jn = 0; jn < 8; ++jn)
    #pragma unroll
    for (int p = 0; p < 4; ++p) {
        int m = wm + im * 16 + quad * 4 + p;   // C/D: col=lane&15, row=quad*4+reg
        int n = wn1 + jn * 16 + lm;
        int ks = n >> 5, kq = (n >> 3) & 3, e = n & 7;
        int pos = kq ^ ((m >> 2) & 3);
        Tls[ks * 4096 + m * 32 + pos * 8 + e] = (bf16)acc1[im][jn][p];
    }
    __syncthreads();                          // also drains sB0/sC0 prefetch

    // ------- Phase 2: S = T @ B^T  and  G = A @ diag(w) @ B^T -------
    f32x4 acc2[4][2] = {}, accG[4][2] = {};

    for (int t = 0; t < 16; ++t) {
        if (t < 15) {
            STAGE2((t + 1) * 32, (t & 1) ? sB0 : sB1, (t & 1) ? sC0 : sC1);
            asm volatile("s_waitcnt vmcnt(2)" ::: "memory");
        } else {
            asm volatile("s_waitcnt vmcnt(0)" ::: "memory");
        }
        __builtin_amdgcn_s_barrier();
        const bf16* B_ = (t & 1) ? sB1 : sB0;
        const bf16* C_ = (t & 1) ? sC1 : sC0;
        float4 w0 = *(const float4*)(w_pred + t * 32 + quad * 8);
        float4 w1 = *(const float4*)(w_pred + t * 32 + quad * 8 + 4);
        float wv[8] = {w0.x, w0.y, w0.z, w0.w, w1.x, w1.y, w1.z, w1.w};
        bf16x8 af[4], af2[4], bf2[2], bfw[2];
        #pragma unroll
        for (int t4 = 0; t4 < 4; ++t4) {
            int R = wm + t4 * 16 + lm;
            af[t4]  = *(const bf16x8*)&Tls[t * 4096 + R * 32 + (quad ^ ((R >> 2) & 3)) * 8];
            af2[t4] = *(const bf16x8*)&C_[R * 32 + (quad ^ ((R >> 1) & 3)) * 8];
        }
        #pragma unroll
        for (int t2 = 0; t2 < 2; ++t2) {
            int R = wn2 + t2 * 16 + lm;
            bf2[t2] = *(const bf16x8*)&B_[R * 32 + (quad ^ ((R >> 1) & 3)) * 8];
            #pragma unroll
            for (int j = 0; j < 8; ++j)
                bfw[t2][j] = (bf16)((float)bf2[t2][j] * wv[j]);
        }
        __builtin_amdgcn_s_setprio(1);
        #pragma unroll
        for (int im = 0; im < 4; ++im)
            #pragma unroll
            for (int jn = 0; jn < 2; ++jn) {
                acc2[im][jn] = __builtin_amdgcn_mfma_f32_16x16x32_bf16(
                    af[im], bf2[jn], acc2[im][jn], 0, 0, 0);
                accG[im][jn] = __builtin_amdgcn_mfma_f32_16x16x32_bf16(
                    af2[im], bfw[jn], accG[im][jn], 0, 0, 0);
            }
        __builtin_amdgcn_s_setprio(0);
        __builtin_amdgcn_s_barrier();
    }

    // ---- S epilogue: tanh + store + row/col sums (Tls dead -> smalls) ----
    const float sc = rsqrtf(ssA * ssB);
    float* __restrict__ Sb = Sout + (size_t)b * NL * NL;
    #pragma unroll
    for (int im = 0; im < 4; ++im)
    #pragma unroll
    for (int jn = 0; jn < 2; ++jn)
    #pragma unroll
    for (int p = 0; p < 4; ++p) {
        float v = tanhf(acc2[im][jn][p] * sc);
        acc2[im][jn][p] = v;
        int m = wm + im * 16 + quad * 4 + p;
        int n = wn2 + jn * 16 + lm;
        __builtin_nontemporal_store(v, &Sb[m * NL + n]);
    }
    #pragma unroll
    for (int im = 0; im < 4; ++im)
    #pragma unroll
    for (int p = 0; p < 4; ++p) {
        float r = acc2[im][0][p] + acc2[im][1][p];
        r += __shfl_xor(r, 1); r += __shfl_xor(r, 2);
        r += __shfl_xor(r, 4); r += __shfl_xor(r, 8);
        if (lm == 0) rowb[(w >> 1) * NL + wm + im * 16 + quad * 4 + p] = r;
    }
    #pragma unroll
    for (int jn = 0; jn < 2; ++jn) {
        float cv = 0.f;
        #pragma unroll
        for (int im = 0; im < 4; ++im)
            #pragma unroll
            for (int p = 0; p < 4; ++p) cv += acc2[im][jn][p];
        cv += __shfl_xor(cv, 16); cv += __shfl_xor(cv, 32);
        if (quad == 0) colb[(w & 1) * NL + wn2 + jn * 16 + lm] = cv;
    }
    __syncthreads();

    // ---- softmax over means (wave0: rows, wave1: cols) ----
    if (tid < 64) {
        float a  = (rowb[tid] + rowb[NL + tid] + rowb[2 * NL + tid] + rowb[3 * NL + tid]) * (1.f / NL);
        float c2 = (rowb[tid + 64] + rowb[NL + tid + 64] + rowb[2 * NL + tid + 64] + rowb[3 * NL + tid + 64]) * (1.f / NL);
        float mx = fmaxf(a, c2);
        for (int o = 32; o; o >>= 1) mx = fmaxf(mx, __shfl_xor(mx, o));
        float e0 = expf(a - mx), e1 = expf(c2 - mx);
        float s = e0 + e1;
        for (int o = 32; o; o >>= 1) s += __shfl_xor(s, o);
        float inv = 1.f / s;
        wrow[tid] = e0 * inv; wrow[tid + 64] = e1 * inv;
    } else if (tid < 128) {
        int q = tid - 64;
        float a  = (colb[q] + colb[NL + q]) * (1.f / NL);
        float c2 = (colb[q + 64] + colb[NL + q + 64]) * (1.f / NL);
        float mx = fmaxf(a, c2);
        for (int o = 32; o; o >>= 1) mx = fmaxf(mx, __shfl_xor(mx, o));
        float e0 = expf(a - mx), e1 = expf(c2 - mx);
        float s = e0 + e1;
        for (int o = 32; o; o >>= 1) s += __shfl_xor(s, o);
        float inv = 1.f / s;
        wcol[q] = e0 * inv; wcol[q + 64] = e1 * inv;
    }
    __syncthreads();

    // ---- logit = sc * wrow^T G wcol ----
    float wc0 = wcol[wn2 + lm], wc1 = wcol[wn2 + 16 + lm];
    float g = 0.f;
    #pragma unroll
    for (int im = 0; im < 4; ++im)
    #pragma unroll
    for (int p = 0; p < 4; ++p) {
        float wr = wrow[wm + im * 16 + quad * 4 + p];
        g += wr * (wc0 * accG[im][0][p] + wc1 * accG[im][1][p]);
    }
    for (int o = 32; o; o >>= 1) g += __shfl_xor(g, o);
    if (lane == 0) red2[w] = g;
    __syncthreads();
    if (tid == 0) {
        float tot = 0.f;
        #pragma unroll
        for (int i = 0; i < 8; ++i) tot += red2[i];
        logits[b] = tot * sc + b_pred[0];
    }
}

extern "C" void kernel_launch(void* const* d_in, const int* in_sizes, int n_in,
                              void* d_out, int out_size, void* d_ws, size_t ws_size,
                              hipStream_t stream) {
    const int*   t1c = (const int*)d_in[2];
    const int*   t2c = (const int*)d_in[3];
    const float* emb = (const float*)d_in[4];
    const float* att = (const float*)d_in[5];
    const float* wp  = (const float*)d_in[6];
    const float* bp  = (const float*)d_in[7];

    float* out    = (float*)d_out;
    float* logits = out;
    float* S      = out + NB;      // outputs: logits(512) then S(512*128*128)

    char* ws = (char*)d_ws;
    bf16*  Ab   = (bf16*)(ws);                              // 67,108,864 B
    bf16*  Bb   = (bf16*)(ws + 67108864);                   // 67,108,864 B
    bf16*  attT = (bf16*)(ws + 134217728);                  //    524,288 B
    float* ss   = (float*)(ws + 134742016);                 //      4,096 B

    hipMemsetAsync(ss, 0, 4096, stream);
    // dedicated BW kernel: gather (y=0,1) + att transpose (y=2)
    k_gather<<<dim3(NB, 3, 8), 256, 0, stream>>>(t1c, t2c, emb, Ab, Bb, ss, att, attT);
    // compute: T in LDS, S + G + softmax + logits (Ab/Bb L3-hot)
    k_mega2<<<dim3(NB), 512, 0, stream>>>(Ab, attT, Bb, S, ss, wp, bp, logits);
}